// Round 1
// 222.616 us; speedup vs baseline: 1.0837x; 1.0837x over previous
//
#include <hip/hip_runtime.h>

// ECNR forward, R17 = R16 with dual-chain waves in K2:
//  K2 restructured from 512 thr / 8 waves (2pt x 4nt, 1 tile each) to
//  256 thr / 4 waves (1 per nt), each wave owning TWO independent 32x32
//  point-chains (pt=0 / pt=1) that SHARE the weight fragments.
//   - two independent MFMA dep-chains per wave -> in-wave MFMA/VALU overlap
//   - weight fragments loaded once per wave (was twice per block): L2 traffic /2
//   - barriers sync 4 waves (was 8); 4 independent blocks/CU desync phases
//   - s_setprio(1) around MFMA clusters (T5: role diversity now exists)
//  Numerics, MFMA count, LDS layout (HSTRIDE=136, 36864 B) identical to R16.

typedef unsigned int u32;
typedef unsigned short u16;
typedef __bf16 v8bf  __attribute__((ext_vector_type(8)));
typedef __bf16 v2bf  __attribute__((ext_vector_type(2)));
typedef float  v16f  __attribute__((ext_vector_type(16)));
typedef float  v2f   __attribute__((ext_vector_type(2)));
typedef u32    v4u   __attribute__((ext_vector_type(4)));
typedef u32    v2u   __attribute__((ext_vector_type(2)));

#define MFMA(a, b, c) __builtin_amdgcn_mfma_f32_32x32x16_bf16(a, b, c, 0, 0, 0)

#define HSTRIDE 136                 // u16; 272 B rows: 16B-aligned, bank-balanced
#define OMEGA_S 4.774648292756860f  // 30/(2*pi); identical constant in both kernels

// acc already in revolutions: sin = v_sin(v_fract(acc))
__device__ __forceinline__ float sinrev(float rev) {
    return __builtin_amdgcn_sinf(__builtin_amdgcn_fractf(rev));
}

__device__ __forceinline__ u32 pack2(float c) {
    __bf16 b0 = (__bf16)c;
    float  f0 = (float)b0;
    __bf16 b1 = (__bf16)(c - f0);
    return (u32)__builtin_bit_cast(u16, b0) |
           ((u32)__builtin_bit_cast(u16, b1) << 16);
}

// two floats -> packed lo (bf16x2) and packed hi (residual bf16x2), RNE
__device__ __forceinline__ void pk2(float s0, float s1, u32& lo, u32& hi) {
    v2f s; s[0] = s0; s[1] = s1;
    v2bf l = __builtin_convertvector(s, v2bf);        // v_cvt_pk_bf16_f32
    u32 lov = __builtin_bit_cast(u32, l);
    v2f lf;
    lf[0] = __builtin_bit_cast(float, lov << 16);
    lf[1] = __builtin_bit_cast(float, lov & 0xffff0000u);
    v2f r = s - lf;
    v2bf h = __builtin_convertvector(r, v2bf);
    lo = lov;
    hi = __builtin_bit_cast(u32, h);
}

__device__ __forceinline__ u32 pklo(float s0, float s1) {
    v2f s; s[0] = s0; s[1] = s1;
    v2bf l = __builtin_convertvector(s, v2bf);
    return __builtin_bit_cast(u32, l);
}

#define PLO(a, b) __builtin_amdgcn_perm((a), (b), 0x05040100u)
#define PHI(a, b) __builtin_amdgcn_perm((a), (b), 0x07060302u)

// ---------------------------------------------------------------------------
// K1: dequant. L0/L1/L2 centroids scaled by OMEGA_S; scaled biases -> biasc.
// (unchanged from R16)
// ---------------------------------------------------------------------------
__global__ __launch_bounds__(512)
void ecnr_dequant(const float* __restrict__ cent0, const int* __restrict__ lab0,
                  const float* __restrict__ cent1, const int* __restrict__ lab1,
                  const float* __restrict__ cent2, const int* __restrict__ lab2,
                  const float* __restrict__ cent3, const int* __restrict__ lab3,
                  const float* __restrict__ bias0, const float* __restrict__ bias1,
                  const float* __restrict__ bias2,
                  u16* __restrict__ wpl1, u16* __restrict__ wpl2,
                  u16* __restrict__ w0pl, u16* __restrict__ w3pl,
                  float* __restrict__ biasc)
{
    __shared__ u32 cpk[512];
    const int t = threadIdx.x;

    if (blockIdx.x < 512) {
        const int m = blockIdx.x >> 1, L = blockIdx.x & 1;
        if (t < 256) cpk[t] = pack2((L ? cent2 : cent1)[t] * OMEGA_S);
        __syncthreads();
        const int* lab = (L ? lab2 : lab1) + (size_t)m * 16384;
        u16* base = (L ? wpl2 : wpl1) + (size_t)m * 32768;
        #pragma unroll
        for (int i = 0; i < 4; ++i) {
            const int id = i * 512 + t;
            const int n = id & 127, c = id >> 7;
            u32 g[8];
            #pragma unroll
            for (int j = 0; j < 8; ++j) g[j] = cpk[lab[(8 * c + j) * 128 + n]];
            v4u lo, hi;
            #pragma unroll
            for (int r = 0; r < 4; ++r) {
                lo[r] = PLO(g[2 * r + 1], g[2 * r]);
                hi[r] = PHI(g[2 * r + 1], g[2 * r]);
            }
            *(v4u*)(base + c * 1024 + n * 8)         = lo;
            *(v4u*)(base + 16384 + c * 1024 + n * 8) = hi;
        }
    } else {
        const int m = blockIdx.x - 512;
        if (t < 256) cpk[t] = pack2(cent0[t] * OMEGA_S);
        else         cpk[t] = pack2(cent3[t - 256]);    // L3 unscaled
        __syncthreads();
        if (t < 256) {
            const int n = t & 127, c = t >> 7;
            const int* lab = lab0 + (size_t)m * 2048;
            u32 g[8];
            #pragma unroll
            for (int j = 0; j < 8; ++j) g[j] = cpk[lab[(8 * c + j) * 128 + n]];
            v4u lo, hi;
            #pragma unroll
            for (int r = 0; r < 4; ++r) {
                lo[r] = PLO(g[2 * r + 1], g[2 * r]);
                hi[r] = PHI(g[2 * r + 1], g[2 * r]);
            }
            u16* b0 = w0pl + (size_t)m * 4096;
            *(v4u*)(b0 + c * 1024 + n * 8)        = lo;
            *(v4u*)(b0 + 2048 + c * 1024 + n * 8) = hi;
        } else if (t < 384) {
            const int kk = t - 256;
            const u32 u = cpk[256 + lab3[(size_t)m * 128 + kk]];
            w3pl[(size_t)m * 256 + kk]       = (u16)u;
            w3pl[(size_t)m * 256 + 128 + kk] = (u16)(u >> 16);
        }
        // scaled biases: biasc[m][0..127]=b0*s, [128..255]=b1*s, [256..383]=b2*s
        if (t < 384) {
            const int li = t >> 7, kk = t & 127;
            const float* bsrc = (li == 0) ? bias0 : (li == 1) ? bias1 : bias2;
            biasc[(size_t)m * 384 + t] = bsrc[m * 128 + kk] * OMEGA_S;
        }
    }
}

// ---------------------------------------------------------------------------
// K2: fused forward, dual-chain waves.
// 256 thr = 4 waves (w = nt). Each wave: chain A = points [0,32), chain B =
// points [32,64) of the block's 64-point tile; chains share W fragments.
// LDS: Hlo/Hhi 2x17408 + biasS 1024 + red 1024 = 36864 B -> 4 blocks/CU.
// ---------------------------------------------------------------------------

// epilogue: 16 accs -> sin -> bf16 lo+hi planes
#define EPI_FULL(ACC, LOP, HIP)                                   \
    do {                                                          \
        _Pragma("unroll")                                         \
        for (int gg = 0; gg < 4; ++gg) {                          \
            const float s0 = sinrev((ACC)[4 * gg + 0]);           \
            const float s1 = sinrev((ACC)[4 * gg + 1]);           \
            const float s2 = sinrev((ACC)[4 * gg + 2]);           \
            const float s3 = sinrev((ACC)[4 * gg + 3]);           \
            u32 l0, h0, l1, h1;                                   \
            pk2(s0, s1, l0, h0);                                  \
            pk2(s2, s3, l1, h1);                                  \
            v2u lov, hiv;                                         \
            lov[0] = l0; lov[1] = l1;                             \
            hiv[0] = h0; hiv[1] = h1;                             \
            *(v2u*)((LOP) + 8 * gg) = lov;                        \
            *(v2u*)((HIP) + 8 * gg) = hiv;                        \
        }                                                         \
    } while (0)

// epilogue: lo plane only (L2 -> L3 handoff, not sin-amplified)
#define EPI_LO(ACC, LOP)                                          \
    do {                                                          \
        _Pragma("unroll")                                         \
        for (int gg = 0; gg < 4; ++gg) {                          \
            const float s0 = sinrev((ACC)[4 * gg + 0]);           \
            const float s1 = sinrev((ACC)[4 * gg + 1]);           \
            const float s2 = sinrev((ACC)[4 * gg + 2]);           \
            const float s3 = sinrev((ACC)[4 * gg + 3]);           \
            v2u lov;                                              \
            lov[0] = pklo(s0, s1);                                \
            lov[1] = pklo(s2, s3);                                \
            *(v2u*)((LOP) + 8 * gg) = lov;                        \
        }                                                         \
    } while (0)

__global__ __launch_bounds__(256, 4)
void ecnr_fwd(const float* __restrict__ x,
              const int*   __restrict__ mlp_idx,
              const int*   __restrict__ block_idx,
              const float* __restrict__ latent,
              const float* __restrict__ bias3,
              const u16* __restrict__ wpl1, const u16* __restrict__ wpl2,
              const u16* __restrict__ w0pl, const u16* __restrict__ w3pl,
              const float* __restrict__ biasc,
              float* __restrict__ out)
{
    __shared__ __attribute__((aligned(16))) u16   Hlo[64 * HSTRIDE];
    __shared__ __attribute__((aligned(16))) u16   Hhi[64 * HSTRIDE];
    __shared__ __attribute__((aligned(16))) float biasS[2 * 128];
    __shared__ __attribute__((aligned(16))) float red[2 * 128];

    // XCD swizzle (bijective): xcd=g[2:0], tile=g[7:3], sample=g[12:8]<<3|xcd
    const int g    = blockIdx.x;
    const int b    = ((g >> 8) << 3) | (g & 7);    // sample 0..255
    const int p0   = ((g >> 3) & 31) * 64;         // tile * 64
    const int m    = mlp_idx[b];

    const int t  = threadIdx.x;
    const int l  = t & 63, nt = t >> 6;     // wave = channel tile nt (0..3)
    const int q  = l >> 5, ln = l & 31;
    const int nn   = nt * 32 + ln;          // channel (A operand / W row)
    const int bidx = nt * 32 + 4 * q;       // bias frag base index

    const float* bc = biasc + (size_t)m * 384;
    // ---- stage L1/L2 scaled biases (visibility via B1); global loads ----
    if (t < 128) {
        biasS[t]       = bc[128 + t];
        biasS[128 + t] = bc[256 + t];
    }
    // chain A = point row ln, chain B = point row 32+ln
    const float* xpA = x + (size_t)(b * 2048 + p0 + ln) * 3;
    const float xA0 = xpA[0], xA1 = xpA[1], xA2 = xpA[2];
    const float xB0 = xpA[96], xB1 = xpA[97], xB2 = xpA[98];
    const u16* w0p = w0pl + (size_t)m * 4096 + q * 1024 + nn * 8;
    const v4u w0lo = *(const v4u*)(w0p);
    const v4u w0hi = *(const v4u*)(w0p + 2048);
    float4 b0f[4];
    #pragma unroll
    for (int gg = 0; gg < 4; ++gg)
        b0f[gg] = *(const float4*)(bc + bidx + 8 * gg);
    const float* zp = latent + ((size_t)m * 8 + block_idx[b]) * 13;
    float zr[8];
    #pragma unroll
    for (int j = 0; j < 8; ++j) zr[j] = zp[q * 5 + j];

    // epilogue write bases (4 consecutive n per group, 8 n between groups)
    u16* lopA = Hlo + ln * HSTRIDE + nt * 32 + 4 * q;
    u16* hipA = Hhi + ln * HSTRIDE + nt * 32 + 4 * q;
    u16* lopB = lopA + 32 * HSTRIDE;
    u16* hipB = hipA + 32 * HSTRIDE;

    // ---- layer 0: A = W0 (regs, scaled, shared), B = input^T x2 chains ----
    {
        float finA[8], finB[8];
        if (q == 0) {
            finA[0] = xA0; finA[1] = xA1; finA[2] = xA2;
            finB[0] = xB0; finB[1] = xB1; finB[2] = xB2;
            #pragma unroll
            for (int j = 0; j < 5; ++j) { finA[3 + j] = zr[j]; finB[3 + j] = zr[j]; }
        } else {
            #pragma unroll
            for (int j = 0; j < 8; ++j) { finA[j] = zr[j]; finB[j] = zr[j]; }
        }
        v4u ilA, ihA, ilB, ihB;
        #pragma unroll
        for (int r = 0; r < 4; ++r) {
            u32 plo, phi;
            pk2(finA[2 * r], finA[2 * r + 1], plo, phi);
            ilA[r] = plo; ihA[r] = phi;
            pk2(finB[2 * r], finB[2 * r + 1], plo, phi);
            ilB[r] = plo; ihB[r] = phi;
        }
        const v8bf inloA = __builtin_bit_cast(v8bf, ilA);
        const v8bf inhiA = __builtin_bit_cast(v8bf, ihA);
        const v8bf inloB = __builtin_bit_cast(v8bf, ilB);
        const v8bf inhiB = __builtin_bit_cast(v8bf, ihB);
        const v8bf wl = __builtin_bit_cast(v8bf, w0lo);
        const v8bf wh = __builtin_bit_cast(v8bf, w0hi);
        v16f accA, accB;
        #pragma unroll
        for (int gg = 0; gg < 4; ++gg) {
            accA[4 * gg] = b0f[gg].x; accA[4 * gg + 1] = b0f[gg].y;
            accA[4 * gg + 2] = b0f[gg].z; accA[4 * gg + 3] = b0f[gg].w;
            accB[4 * gg] = b0f[gg].x; accB[4 * gg + 1] = b0f[gg].y;
            accB[4 * gg + 2] = b0f[gg].z; accB[4 * gg + 3] = b0f[gg].w;
        }
        __builtin_amdgcn_s_setprio(1);
        accA = MFMA(wl, inloA, accA); accB = MFMA(wl, inloB, accB);
        accA = MFMA(wl, inhiA, accA); accB = MFMA(wl, inhiB, accB);
        accA = MFMA(wh, inloA, accA); accB = MFMA(wh, inloB, accB);
        __builtin_amdgcn_s_setprio(0);
        EPI_FULL(accA, lopA, hipA);
        EPI_FULL(accB, lopB, hipB);
    }
    __syncthreads();  // B1: H(L0) + biasS visible

    // ---- layers 1,2: A = W (shared, wlo panel resident), B = H^T x2 ----
    const u16* HLA = Hlo + ln * HSTRIDE + q * 8;
    const u16* HHA = Hhi + ln * HSTRIDE + q * 8;
    const u16* HLB = HLA + 32 * HSTRIDE;
    const u16* HHB = HHA + 32 * HSTRIDE;
    #pragma unroll 1
    for (int L = 0; L < 2; ++L) {
        const u16* Wb = (L ? wpl2 : wpl1) + (size_t)m * 32768 + q * 1024 + nn * 8;
        v16f accA, accB;
        #pragma unroll
        for (int gg = 0; gg < 4; ++gg) {
            const float4 bv = *(const float4*)&biasS[L * 128 + bidx + 8 * gg];
            accA[4 * gg] = bv.x; accA[4 * gg + 1] = bv.y;
            accA[4 * gg + 2] = bv.z; accA[4 * gg + 3] = bv.w;
            accB[4 * gg] = bv.x; accB[4 * gg + 1] = bv.y;
            accB[4 * gg + 2] = bv.z; accB[4 * gg + 3] = bv.w;
        }
        v4u wl8[8];
        #pragma unroll
        for (int kc = 0; kc < 8; ++kc)
            wl8[kc] = *(const v4u*)(Wb + kc * 2048);
        #pragma unroll
        for (int kc = 0; kc < 8; ++kc) {
            const v4u whv = *(const v4u*)(Wb + kc * 2048 + 16384);  // issue early
            const v8bf hloA = *(const v8bf*)(HLA + kc * 16);
            const v8bf hhiA = *(const v8bf*)(HHA + kc * 16);
            const v8bf hloB = *(const v8bf*)(HLB + kc * 16);
            const v8bf hhiB = *(const v8bf*)(HHB + kc * 16);
            const v8bf wlv = __builtin_bit_cast(v8bf, wl8[kc]);
            const v8bf whb = __builtin_bit_cast(v8bf, whv);
            __builtin_amdgcn_s_setprio(1);
            accA = MFMA(wlv, hloA, accA); accB = MFMA(wlv, hloB, accB);
            accA = MFMA(wlv, hhiA, accA); accB = MFMA(wlv, hhiB, accB);
            accA = MFMA(whb, hloA, accA); accB = MFMA(whb, hloB, accB);
            __builtin_amdgcn_s_setprio(0);
        }
        __syncthreads();  // B2/B4: all H reads of this layer done
        if (L == 0) {
            EPI_FULL(accA, lopA, hipA);
            EPI_FULL(accB, lopB, hipB);
        } else {          // L2 -> L3 handoff: lo plane only
            EPI_LO(accA, lopA);
            EPI_LO(accB, lopB);
        }
        __syncthreads();  // B3/B5: H(L) visible
    }

    // ---- layer 3 on MFMA: A = w3 (bf16x2, unscaled, shared), B = H^T lo x2 ----
    {
        const u16* w3b = w3pl + (size_t)m * 256 + nt * 32 + q * 8;
        const u16* h3A = Hlo + ln * HSTRIDE + nt * 32 + q * 8;
        const u16* h3B = h3A + 32 * HSTRIDE;
        v16f aA, aB;
        #pragma unroll
        for (int r = 0; r < 16; ++r) { aA[r] = 0.0f; aB[r] = 0.0f; }
        #pragma unroll
        for (int kc = 0; kc < 2; ++kc) {
            const v8bf wl = *(const v8bf*)(w3b + kc * 16);
            const v8bf wh = *(const v8bf*)(w3b + 128 + kc * 16);
            const v8bf hA = *(const v8bf*)(h3A + kc * 16);
            const v8bf hB = *(const v8bf*)(h3B + kc * 16);
            __builtin_amdgcn_s_setprio(1);
            aA = MFMA(wl, hA, aA); aB = MFMA(wl, hB, aB);
            aA = MFMA(wh, hA, aA); aB = MFMA(wh, hB, aB);
            __builtin_amdgcn_s_setprio(0);
        }
        if (q == 0) {
            red[nt * 32 + ln]       = aA[0];
            red[128 + nt * 32 + ln] = aB[0];
        }
    }
    __syncthreads();  // B6

    if (t < 64) {
        const int rp = (t >> 5) * 128, rl = t & 31;
        const float o = bias3[m]
            + red[rp + rl] + red[rp + 32 + rl]
            + red[rp + 64 + rl] + red[rp + 96 + rl];
        out[(size_t)b * 2048 + p0 + t] = o;
    }
}

extern "C" void kernel_launch(void* const* d_in, const int* in_sizes, int n_in,
                              void* d_out, int out_size, void* d_ws, size_t ws_size,
                              hipStream_t stream) {
    (void)in_sizes; (void)n_in; (void)out_size; (void)ws_size;
    u16*   wpl1  = (u16*)d_ws;                          // 16 MB
    u16*   wpl2  = wpl1 + (size_t)256 * 32768;          // 16 MB
    u16*   w0pl  = wpl2 + (size_t)256 * 32768;          // 2 MB
    u16*   w3pl  = w0pl + (size_t)256 * 4096;           // 128 KB
    float* biasc = (float*)(w3pl + (size_t)256 * 256);  // 384 KB (scaled biases)

    ecnr_dequant<<<768, 512, 0, stream>>>(
        (const float*)d_in[4],  (const int*)d_in[5],
        (const float*)d_in[7],  (const int*)d_in[8],
        (const float*)d_in[10], (const int*)d_in[11],
        (const float*)d_in[13], (const int*)d_in[14],
        (const float*)d_in[6],  (const float*)d_in[9], (const float*)d_in[12],
        wpl1, wpl2, w0pl, w3pl, biasc);

    ecnr_fwd<<<8192, 256, 0, stream>>>(
        (const float*)d_in[0], (const int*)d_in[1], (const int*)d_in[2],
        (const float*)d_in[3],
        (const float*)d_in[15],
        wpl1, wpl2, w0pl, w3pl, biasc,
        (float*)d_out);
}